// Round 1
// baseline (974.797 us; speedup 1.0000x reference)
//
#include <hip/hip_runtime.h>
#include <math.h>

// Problem shape (fixed by setup_inputs): P=512, R=256, S=256, K=3, threshold=0.
#define Pn 512
#define Rn 256
#define Sn 256

// Insert (v,i) into a descending top-3 (t0>=t1>=t2). Strict > keeps the
// earlier-inserted (lower-index) element on ties, matching lax.top_k.
__device__ __forceinline__ void ins3(float v, int i,
    float& t0, int& i0, float& t1, int& i1, float& t2, int& i2) {
  if (v > t2) {
    if (v > t1) {
      if (v > t0) { t2 = t1; i2 = i1; t1 = t0; i1 = i0; t0 = v; i0 = i; }
      else        { t2 = t1; i2 = i1; t1 = v;  i1 = i; }
    } else        { t2 = v;  i2 = i; }
  }
}

// Pass 1: top-3 along S for each row (p,r). One wave (64 lanes) per row,
// float4 per lane. Butterfly shfl_xor merge; lane 0 writes exp(val) + idx.
__global__ __launch_bounds__(256) void rowtop3_kernel(
    const float* __restrict__ score,
    float* __restrict__ refv, int* __restrict__ refi) {
  const int row  = (blockIdx.x * blockDim.x + threadIdx.x) >> 6;  // p*Rn + r
  const int lane = threadIdx.x & 63;
  const float4 v = reinterpret_cast<const float4*>(score + (size_t)row * Sn)[lane];
  float t0 = -INFINITY, t1 = -INFINITY, t2 = -INFINITY;
  int   i0 = -1, i1 = -1, i2 = -1;
  const int b = lane * 4;
  ins3(v.x, b + 0, t0, i0, t1, i1, t2, i2);
  ins3(v.y, b + 1, t0, i0, t1, i1, t2, i2);
  ins3(v.z, b + 2, t0, i0, t1, i1, t2, i2);
  ins3(v.w, b + 3, t0, i0, t1, i1, t2, i2);
  #pragma unroll
  for (int off = 1; off < 64; off <<= 1) {
    float o0 = __shfl_xor(t0, off), o1 = __shfl_xor(t1, off), o2 = __shfl_xor(t2, off);
    int   j0 = __shfl_xor(i0, off), j1 = __shfl_xor(i1, off), j2 = __shfl_xor(i2, off);
    ins3(o0, j0, t0, i0, t1, i1, t2, i2);
    ins3(o1, j1, t0, i0, t1, i1, t2, i2);
    ins3(o2, j2, t0, i0, t1, i1, t2, i2);
  }
  if (lane == 0) {
    const size_t o = (size_t)row * 3;
    refv[o + 0] = expf(t0); refv[o + 1] = expf(t1); refv[o + 2] = expf(t2);
    refi[o + 0] = i0;       refi[o + 1] = i1;       refi[o + 2] = i2;
  }
}

// Pass 2: top-3 along R for each column (p,s). One block per p, thread s
// owns one column; 256 coalesced row loads. Output stored k-major
// (srcv[k*P*S + p*S + s]) so pass 3 can vector-load it.
__global__ __launch_bounds__(256) void coltop3_kernel(
    const float* __restrict__ score,
    float* __restrict__ srcv, int* __restrict__ srci) {
  const int p = blockIdx.x;
  const int s = threadIdx.x;
  const float* base = score + (size_t)p * Rn * Sn + s;
  float t0 = -INFINITY, t1 = -INFINITY, t2 = -INFINITY;
  int   i0 = -1, i1 = -1, i2 = -1;
  #pragma unroll 8
  for (int r = 0; r < Rn; ++r) {
    float v = base[(size_t)r * Sn];
    ins3(v, r, t0, i0, t1, i1, t2, i2);
  }
  const size_t PS = (size_t)Pn * Sn;
  const size_t o  = (size_t)p * Sn + s;
  srcv[0 * PS + o] = expf(t0); srci[0 * PS + o] = i0;
  srcv[1 * PS + o] = expf(t1); srci[1 * PS + o] = i1;
  srcv[2 * PS + o] = expf(t2); srci[2 * PS + o] = i2;
}

__device__ __forceinline__ void compute_elem(
    int s, int r, bool rmask, int sm,
    float rv0, float rv1, float rv2, int ri0, int ri1, int ri2,
    float a0, int b0, float a1, int b1, float a2, int b2,
    float& oscore, float& ocorr) {
  const float rv = (s == ri0) ? rv0 : (s == ri1) ? rv1 : (s == ri2) ? rv2 : 0.0f;
  const float sv = (r == b0) ? a0 : (r == b1) ? a1 : (r == b2) ? a2 : 0.0f;
  oscore = 0.5f * (rv + sv);
  const bool m = rmask && (sm != 0);
  ocorr = (((rv > 0.0f) || (sv > 0.0f)) && m) ? 1.0f : 0.0f;
}

// Pass 3: dense write of score_map and corr_map (as 0/1 float).
// One wave per output row, float4/int4 loads and float4 stores.
__global__ __launch_bounds__(256) void write_kernel(
    const float* __restrict__ refv, const int* __restrict__ refi,
    const float* __restrict__ srcv, const int* __restrict__ srci,
    const int* __restrict__ rmaskp, const int* __restrict__ smaskp,
    float* __restrict__ out) {
  const int row  = blockIdx.x * 4 + (threadIdx.x >> 6);  // p*Rn + r
  const int lane = threadIdx.x & 63;
  const int p = row >> 8;           // Rn == 256
  const int r = row & (Rn - 1);
  const size_t PS = (size_t)Pn * Sn;
  const size_t N  = (size_t)Pn * Rn * Sn;

  const size_t rb = (size_t)row * 3;
  const float rv0 = refv[rb + 0], rv1 = refv[rb + 1], rv2 = refv[rb + 2];
  const int   ri0 = refi[rb + 0], ri1 = refi[rb + 1], ri2 = refi[rb + 2];
  const bool  rmask = rmaskp[row] != 0;

  const float4 sv0 = reinterpret_cast<const float4*>(srcv + 0 * PS + (size_t)p * Sn)[lane];
  const float4 sv1 = reinterpret_cast<const float4*>(srcv + 1 * PS + (size_t)p * Sn)[lane];
  const float4 sv2 = reinterpret_cast<const float4*>(srcv + 2 * PS + (size_t)p * Sn)[lane];
  const int4   si0 = reinterpret_cast<const int4*>(srci + 0 * PS + (size_t)p * Sn)[lane];
  const int4   si1 = reinterpret_cast<const int4*>(srci + 1 * PS + (size_t)p * Sn)[lane];
  const int4   si2 = reinterpret_cast<const int4*>(srci + 2 * PS + (size_t)p * Sn)[lane];
  const int4   sm  = reinterpret_cast<const int4*>(smaskp + (size_t)p * Sn)[lane];

  const int sbase = lane * 4;
  float4 osc, oco;
  compute_elem(sbase + 0, r, rmask, sm.x, rv0, rv1, rv2, ri0, ri1, ri2,
               sv0.x, si0.x, sv1.x, si1.x, sv2.x, si2.x, osc.x, oco.x);
  compute_elem(sbase + 1, r, rmask, sm.y, rv0, rv1, rv2, ri0, ri1, ri2,
               sv0.y, si0.y, sv1.y, si1.y, sv2.y, si2.y, osc.y, oco.y);
  compute_elem(sbase + 2, r, rmask, sm.z, rv0, rv1, rv2, ri0, ri1, ri2,
               sv0.z, si0.z, sv1.z, si1.z, sv2.z, si2.z, osc.z, oco.z);
  compute_elem(sbase + 3, r, rmask, sm.w, rv0, rv1, rv2, ri0, ri1, ri2,
               sv0.w, si0.w, sv1.w, si1.w, sv2.w, si2.w, osc.w, oco.w);

  reinterpret_cast<float4*>(out + (size_t)row * Sn)[lane]     = osc;
  reinterpret_cast<float4*>(out + N + (size_t)row * Sn)[lane] = oco;
}

extern "C" void kernel_launch(void* const* d_in, const int* in_sizes, int n_in,
                              void* d_out, int out_size, void* d_ws, size_t ws_size,
                              hipStream_t stream) {
  const float* score = (const float*)d_in[0];
  // d_in[1] = node_corr_scores: unused (conditional=False in reference)
  const int* rmask = (const int*)d_in[2];
  const int* smask = (const int*)d_in[3];
  float* out = (float*)d_out;

  const size_t PR = (size_t)Pn * Rn;
  const size_t PS = (size_t)Pn * Sn;
  // Workspace layout (~6.3 MB total):
  float* refv = (float*)d_ws;            // 3*PR floats
  int*   refi = (int*)(refv + 3 * PR);   // 3*PR ints
  float* srcv = (float*)(refi + 3 * PR); // 3*PS floats (k-major planes)
  int*   srci = (int*)(srcv + 3 * PS);   // 3*PS ints  (k-major planes)

  rowtop3_kernel<<<(Pn * Rn) / 4, 256, 0, stream>>>(score, refv, refi);
  coltop3_kernel<<<Pn, 256, 0, stream>>>(score, srcv, srci);
  write_kernel<<<(Pn * Rn) / 4, 256, 0, stream>>>(refv, refi, srcv, srci,
                                                  rmask, smask, out);
}

// Round 2
// 430.892 us; speedup vs baseline: 2.2623x; 2.2623x over previous
//
#include <hip/hip_runtime.h>
#include <math.h>
#include <stdint.h>

// Problem shape (fixed by setup_inputs): P=512, R=256, S=256, K=3, threshold=0.
#define Pn 512
#define Rn 256
#define Sn 256

typedef unsigned long long u64;
typedef unsigned int u32;

// Monotonic float -> u32 map (order-preserving for all finite floats).
__device__ __forceinline__ u32 mono(float f) {
  u32 u = __float_as_uint(f);
  return (u & 0x80000000u) ? ~u : (u | 0x80000000u);
}
__device__ __forceinline__ float unmono(u32 m) {
  u32 bits = (m & 0x80000000u) ? (m & 0x7FFFFFFFu) : ~m;
  return __uint_as_float(bits);
}
// Packed sort key: value-monotonic bits in high 32, ~index in low 32.
// Larger key = larger value; on equal value, smaller index wins (lax.top_k).
__device__ __forceinline__ u64 makekey(float v, int idx) {
  return ((u64)mono(v) << 32) | (u32)(~(u32)idx);
}
__device__ __forceinline__ int key_idx(u64 k) { return (int)(~(u32)k); }
__device__ __forceinline__ float key_val(u64 k) { return unmono((u32)(k >> 32)); }

// Branchless compare-exchange: a = max, b = min.
__device__ __forceinline__ void cswap(u64& a, u64& b) {
  const bool c = a > b;
  const u64 hi = c ? a : b;
  const u64 lo = c ? b : a;
  a = hi; b = lo;
}

// Pass 1: top-3 along S for each row (p,r). One wave per row, float4/lane.
// Per-lane sort-4 (5 cswaps), then 3 rounds of u64 wave-max + pop.
__global__ void rowtop3_kernel(const float* __restrict__ score,
                               float* __restrict__ refv, int* __restrict__ refi) {
  const int row  = (blockIdx.x * blockDim.x + threadIdx.x) >> 6;  // p*Rn + r
  const int lane = threadIdx.x & 63;
  const float4 v = reinterpret_cast<const float4*>(score + (size_t)row * Sn)[lane];
  const int b = lane * 4;
  u64 a0 = makekey(v.x, b + 0);
  u64 a1 = makekey(v.y, b + 1);
  u64 a2 = makekey(v.z, b + 2);
  u64 a3 = makekey(v.w, b + 3);
  // Sort-4 descending network; keep top 3.
  cswap(a0, a1); cswap(a2, a3); cswap(a0, a2); cswap(a1, a3); cswap(a1, a2);
  u64 t0 = a0, t1 = a1, t2 = a2;

  u64 res0 = 0, res1 = 0, res2 = 0;
  #pragma unroll
  for (int j = 0; j < 3; ++j) {
    u64 m = t0;
    #pragma unroll
    for (int off = 1; off < 64; off <<= 1) {
      const u64 o = __shfl_xor(m, off);
      m = (o > m) ? o : m;
    }
    // Exactly one lane holds m (keys unique via embedded index): pop it.
    const bool hit = (t0 == m);
    t0 = hit ? t1 : t0;
    t1 = hit ? t2 : t1;
    t2 = hit ? 0ull : t2;
    if (j == 0) res0 = m; else if (j == 1) res1 = m; else res2 = m;
  }
  if (lane == 0) {
    const size_t o = (size_t)row * 3;
    refv[o + 0] = expf(key_val(res0)); refi[o + 0] = key_idx(res0);
    refv[o + 1] = expf(key_val(res1)); refi[o + 1] = key_idx(res1);
    refv[o + 2] = expf(key_val(res2)); refi[o + 2] = key_idx(res2);
  }
}

// Pass 2: top-3 along R for each column (p,s). One block per p, thread s owns
// one column; 256 coalesced row loads; branchless 3-cswap insert.
// Output k-major (srcv[k*P*S + p*S + s]) so pass 3 vector-loads it.
__global__ void coltop3_kernel(const float* __restrict__ score,
                               float* __restrict__ srcv, int* __restrict__ srci) {
  const int p = blockIdx.x;
  const int s = threadIdx.x;
  const float* base = score + (size_t)p * Rn * Sn + s;
  u64 t0 = 0, t1 = 0, t2 = 0;
  #pragma unroll 8
  for (int r = 0; r < Rn; ++r) {
    u64 k = makekey(base[(size_t)r * Sn], r);
    cswap(t0, k); cswap(t1, k); cswap(t2, k);
  }
  const size_t PS = (size_t)Pn * Sn;
  const size_t o  = (size_t)p * Sn + s;
  srcv[0 * PS + o] = expf(key_val(t0)); srci[0 * PS + o] = key_idx(t0);
  srcv[1 * PS + o] = expf(key_val(t1)); srci[1 * PS + o] = key_idx(t1);
  srcv[2 * PS + o] = expf(key_val(t2)); srci[2 * PS + o] = key_idx(t2);
}

__device__ __forceinline__ void compute_elem(
    int s, int r, bool rmask, int sm,
    float rv0, float rv1, float rv2, int ri0, int ri1, int ri2,
    float a0, int b0, float a1, int b1, float a2, int b2,
    float& oscore, float& ocorr) {
  const float rv = (s == ri0) ? rv0 : (s == ri1) ? rv1 : (s == ri2) ? rv2 : 0.0f;
  const float sv = (r == b0) ? a0 : (r == b1) ? a1 : (r == b2) ? a2 : 0.0f;
  oscore = 0.5f * (rv + sv);
  const bool m = rmask && (sm != 0);
  ocorr = (((rv > 0.0f) || (sv > 0.0f)) && m) ? 1.0f : 0.0f;
}

// Pass 3: dense write of score_map and corr_map (as 0/1 float).
// One wave per output row, float4/int4 loads and float4 stores.
__global__ void write_kernel(
    const float* __restrict__ refv, const int* __restrict__ refi,
    const float* __restrict__ srcv, const int* __restrict__ srci,
    const int* __restrict__ rmaskp, const int* __restrict__ smaskp,
    float* __restrict__ out) {
  const int row  = blockIdx.x * 4 + (threadIdx.x >> 6);  // p*Rn + r
  const int lane = threadIdx.x & 63;
  const int p = row >> 8;           // Rn == 256
  const int r = row & (Rn - 1);
  const size_t PS = (size_t)Pn * Sn;
  const size_t N  = (size_t)Pn * Rn * Sn;

  const size_t rb = (size_t)row * 3;
  const float rv0 = refv[rb + 0], rv1 = refv[rb + 1], rv2 = refv[rb + 2];
  const int   ri0 = refi[rb + 0], ri1 = refi[rb + 1], ri2 = refi[rb + 2];
  const bool  rmask = rmaskp[row] != 0;

  const float4 sv0 = reinterpret_cast<const float4*>(srcv + 0 * PS + (size_t)p * Sn)[lane];
  const float4 sv1 = reinterpret_cast<const float4*>(srcv + 1 * PS + (size_t)p * Sn)[lane];
  const float4 sv2 = reinterpret_cast<const float4*>(srcv + 2 * PS + (size_t)p * Sn)[lane];
  const int4   si0 = reinterpret_cast<const int4*>(srci + 0 * PS + (size_t)p * Sn)[lane];
  const int4   si1 = reinterpret_cast<const int4*>(srci + 1 * PS + (size_t)p * Sn)[lane];
  const int4   si2 = reinterpret_cast<const int4*>(srci + 2 * PS + (size_t)p * Sn)[lane];
  const int4   sm  = reinterpret_cast<const int4*>(smaskp + (size_t)p * Sn)[lane];

  const int sbase = lane * 4;
  float4 osc, oco;
  compute_elem(sbase + 0, r, rmask, sm.x, rv0, rv1, rv2, ri0, ri1, ri2,
               sv0.x, si0.x, sv1.x, si1.x, sv2.x, si2.x, osc.x, oco.x);
  compute_elem(sbase + 1, r, rmask, sm.y, rv0, rv1, rv2, ri0, ri1, ri2,
               sv0.y, si0.y, sv1.y, si1.y, sv2.y, si2.y, osc.y, oco.y);
  compute_elem(sbase + 2, r, rmask, sm.z, rv0, rv1, rv2, ri0, ri1, ri2,
               sv0.z, si0.z, sv1.z, si1.z, sv2.z, si2.z, osc.z, oco.z);
  compute_elem(sbase + 3, r, rmask, sm.w, rv0, rv1, rv2, ri0, ri1, ri2,
               sv0.w, si0.w, sv1.w, si1.w, sv2.w, si2.w, osc.w, oco.w);

  reinterpret_cast<float4*>(out + (size_t)row * Sn)[lane]     = osc;
  reinterpret_cast<float4*>(out + N + (size_t)row * Sn)[lane] = oco;
}

extern "C" void kernel_launch(void* const* d_in, const int* in_sizes, int n_in,
                              void* d_out, int out_size, void* d_ws, size_t ws_size,
                              hipStream_t stream) {
  const float* score = (const float*)d_in[0];
  // d_in[1] = node_corr_scores: unused (conditional=False in reference)
  const int* rmask = (const int*)d_in[2];
  const int* smask = (const int*)d_in[3];
  float* out = (float*)d_out;

  const size_t PR = (size_t)Pn * Rn;
  const size_t PS = (size_t)Pn * Sn;
  // Workspace layout (~6.3 MB total):
  float* refv = (float*)d_ws;            // 3*PR floats
  int*   refi = (int*)(refv + 3 * PR);   // 3*PR ints
  float* srcv = (float*)(refi + 3 * PR); // 3*PS floats (k-major planes)
  int*   srci = (int*)(srcv + 3 * PS);   // 3*PS ints  (k-major planes)

  rowtop3_kernel<<<(Pn * Rn) / 4, 256, 0, stream>>>(score, refv, refi);
  coltop3_kernel<<<Pn, 256, 0, stream>>>(score, srcv, srci);
  write_kernel<<<(Pn * Rn) / 4, 256, 0, stream>>>(refv, refi, srcv, srci,
                                                  rmask, smask, out);
}